// Round 3
// baseline (24619.646 us; speedup 1.0000x reference)
//
#include <hip/hip_runtime.h>
#include <hip/hip_fp16.h>

// ONLSTM fused 2-layer recurrent kernel for MI355X (gfx950), round 6.
// r5 post-mortem: counter-barrier + cached-fresh-slot reads REGRESSED
// (6646 vs r3's 5807). r3's flag barriers were already near-optimal; the
// real cost is barrier POPULATION (256 WGs x 2 global barriers/step).
// r6: drop the weights-in-LDS constraint (weights stream from L3: 44 MB/step
// ~= 3-4 us, overlapped with MFMA) -> 32 cols/WG -> 64 WGs total.
//   - 4x smaller barrier population, r3-proven flag-array barriers.
//   - N-split across 4 waves (no sZ atomics; direct epilogue stores).
//   - A (h vector) staged once per WG via LDS double-buffer (sc1 loads,
//     issue-early/write-late), not read 4x redundantly per wave.
//   - sc1 for ALL intra-run cross-WG data (h, PART, flags): no cache
//     staleness across steps or launches. Ring h slots, r3 ws layout.

typedef _Float16 f16;
typedef _Float16 f16x8 __attribute__((ext_vector_type(8)));
typedef _Float16 f16x2 __attribute__((ext_vector_type(2)));
typedef float f32x4 __attribute__((ext_vector_type(4)));

#define NWG 64
#define AGENT __HIP_MEMORY_SCOPE_AGENT
#define MFMA16 __builtin_amdgcn_mfma_f32_16x16x32_f16

// coherent (sc1) 16B fragment load: two relaxed agent-scope u64 atomic loads
__device__ __forceinline__ f16x8 ld_frag(const f16* p) {
    union { unsigned long long u[2]; f16x8 v; } c;
    c.u[0] = __hip_atomic_load((const unsigned long long*)p, __ATOMIC_RELAXED, AGENT);
    c.u[1] = __hip_atomic_load(((const unsigned long long*)p) + 1, __ATOMIC_RELAXED, AGENT);
    return c.v;
}

// cooperative A-chunk staging: 16384 f16 (8 K-tiles) per chunk, 64 f16/thread
__device__ __forceinline__ void stage_issue(const f16* src, f16x8 st[8], int tid) {
#pragma unroll
    for (int i = 0; i < 8; ++i)
        st[i] = ld_frag(src + (size_t)tid * 64 + i * 8);
}
__device__ __forceinline__ void stage_write(f16* dst, const f16x8 st[8], int tid) {
#pragma unroll
    for (int i = 0; i < 8; ++i)
        *(f16x8*)(dst + (size_t)tid * 64 + i * 8) = st[i];
}

// ---------------- pack kernels (unchanged, verified) ----------------
__global__ void onlstm_pack_w(const float* __restrict__ W, f16* __restrict__ dst,
                              int nkt, int krow0) {
    int idx = blockIdx.x * blockDim.x + threadIdx.x;
    int total = 128 * 3 * nkt * 64;
    if (idx >= total) return;
    int lane = idx & 63;
    int kt = (idx >> 6) % nkt;
    int ct = ((idx >> 6) / nkt) % 3;
    int w  = (idx >> 6) / (nkt * 3);
    int cc = lane & 15;
    int gate = 2 * ct + (cc >> 3);
    int col = gate * 1024 + (w << 3) + (cc & 7);
    int krow = krow0 + kt * 32 + ((lane >> 4) << 3);
    const float* src = W + (size_t)krow * 6144 + col;
    f16x8 v;
#pragma unroll
    for (int i = 0; i < 8; ++i) v[i] = (f16)src[(size_t)i * 6144];
    *(f16x8*)(dst + (size_t)idx * 8) = v;
}

__global__ void onlstm_pack_x(const float* __restrict__ x, f16* __restrict__ dst) {
    int idx = blockIdx.x * blockDim.x + threadIdx.x;
    if (idx >= 256 * 16 * 4 * 64) return;
    int lane = idx & 63;
    int rt = (idx >> 6) & 3;
    int kt = (idx >> 8) & 15;
    int t  = idx >> 12;
    int m = rt * 16 + (lane & 15);
    int k = kt * 32 + ((lane >> 4) << 3);
    const float* src = x + ((size_t)t * 64 + m) * 512 + k;
    f16x8 v;
#pragma unroll
    for (int i = 0; i < 8; ++i) v[i] = (f16)src[i];
    *(f16x8*)(dst + (size_t)idx * 8) = v;
}

__device__ __forceinline__ float fast_sigmoid(float x) {
    return 1.0f / (1.0f + __expf(-x));
}
__device__ __forceinline__ float fast_tanh(float x) {
    return 1.0f - 2.0f / (__expf(2.0f * x) + 1.0f);
}

// ---------------- main persistent kernel ----------------
// 64 WGs: wg 0..31 = layer0 (32 cols each), wg 32..63 = layer1.
// LDS (dynamic, 116736 B): sA dbuf 2x32768 | sZ 64x193 f32 49408 |
//                          sScl 1024 | sBias 768
// FLAGS: FA at FLAGS[wg*16], FB at FLAGS[4096 + wg*16] (64B-spaced ints)
__global__ __launch_bounds__(256, 1) void onlstm_main(
    const f16* __restrict__ WB0, const f16* __restrict__ WB1,
    const f16* __restrict__ WS1, const f16* __restrict__ XP,
    f16* __restrict__ H0P, f16* __restrict__ H1P,
    float* __restrict__ PART, int* __restrict__ FLAGS,
    const float* __restrict__ b0, const float* __restrict__ b1,
    float* __restrict__ out)
{
    extern __shared__ char smem[];
    f16*   sA    = (f16*)smem;                    // 2 x 16384 f16
    float* sZ    = (float*)(smem + 65536);        // 64 x 193
    float* sScl  = (float*)(smem + 114944);       // 64 x 4
    float* sBias = (float*)(smem + 115968);       // 192

    const int tid = threadIdx.x;
    const int wg = blockIdx.x;
    const int layer = wg >> 5;
    const int w = wg & 31;            // layer-local WG index
    const int lane = tid & 63;
    const int v = tid >> 6;           // wave 0..3: owns 8-col group v
    const int m_u = tid & 63;
    const int j0 = w << 5;            // 32 real cols per WG
    const int w8 = (w << 2) + v;      // global 8-col group index (pack 'w')
    int* FA = FLAGS;
    int* FB = FLAGS + 4096;

    if (tid < 192) {
        int vv = tid / 48, r = tid % 48;          // r = ct*16 + hi*8 + jj
        sBias[tid] = (layer ? b1 : b0)[(r >> 3) * 1024 + j0 + vv * 8 + (r & 7)];
    }
    float c[8];                       // cell state: (m_u, j0 + v*8 + jj)
#pragma unroll
    for (int i = 0; i < 8; ++i) c[i] = 0.f;
    __syncthreads();

    for (int s = 0; s <= 256; ++s) {
        const int active = layer ? (s >= 1) : (s < 256);
        const int t = layer ? (s - 1) : s;

        if (active) {
            // ---------- GEMM: N-split (wave v owns cols [j0+8v, j0+8v+8)) ----------
            f32x4 acc[4][3];
#pragma unroll
            for (int r = 0; r < 4; ++r)
#pragma unroll
                for (int cix = 0; cix < 3; ++cix) { f32x4 z = {0.f,0.f,0.f,0.f}; acc[r][cix] = z; }

            const f16* h0r = H0P + (size_t)((s + 2) % 3) * 65536;   // h0(s-1)
            const int lo8 = lane << 3;
            f16x8 st[8];

            if (layer == 0) {
                const f16* Bb = WB0 + (size_t)(w8 * 3) * 48 * 512;
                const f16* XPt = XP + (size_t)t * 32768;
                stage_issue(h0r, st, tid);                 // h chunk 0 in flight
                // XP part: 16 K-tiles, plain cached loads (pre-kernel data)
#pragma unroll 4
                for (int kt = 0; kt < 16; ++kt) {
                    const f16* ap = XPt + (size_t)(kt * 4) * 512 + lo8;
                    f16x8 a0 = *(const f16x8*)(ap);
                    f16x8 a1 = *(const f16x8*)(ap + 512);
                    f16x8 a2 = *(const f16x8*)(ap + 1024);
                    f16x8 a3 = *(const f16x8*)(ap + 1536);
#pragma unroll
                    for (int ct = 0; ct < 3; ++ct) {
                        f16x8 b = *(const f16x8*)(Bb + (((size_t)(ct * 48 + kt)) << 9) + lo8);
                        acc[0][ct] = MFMA16(a0, b, acc[0][ct], 0, 0, 0);
                        acc[1][ct] = MFMA16(a1, b, acc[1][ct], 0, 0, 0);
                        acc[2][ct] = MFMA16(a2, b, acc[2][ct], 0, 0, 0);
                        acc[3][ct] = MFMA16(a3, b, acc[3][ct], 0, 0, 0);
                    }
                }
                stage_write(sA, st, tid);
                __syncthreads();
                // h part: 4 staged chunks of 8 K-tiles
                for (int cn = 0; cn < 4; ++cn) {
                    if (cn < 3) stage_issue(h0r + (size_t)(cn + 1) * 16384, st, tid);
                    const f16* Ab = sA + (cn & 1) * 16384;
                    const f16* Bch = Bb + (size_t)(16 + cn * 8) * 512;
#pragma unroll
                    for (int k = 0; k < 8; ++k) {
                        const f16* ap = Ab + (size_t)(k * 4) * 512 + lo8;
                        f16x8 a0 = *(const f16x8*)(ap);
                        f16x8 a1 = *(const f16x8*)(ap + 512);
                        f16x8 a2 = *(const f16x8*)(ap + 1024);
                        f16x8 a3 = *(const f16x8*)(ap + 1536);
#pragma unroll
                        for (int ct = 0; ct < 3; ++ct) {
                            f16x8 b = *(const f16x8*)(Bch + (((size_t)(ct * 48 + k)) << 9) + lo8);
                            acc[0][ct] = MFMA16(a0, b, acc[0][ct], 0, 0, 0);
                            acc[1][ct] = MFMA16(a1, b, acc[1][ct], 0, 0, 0);
                            acc[2][ct] = MFMA16(a2, b, acc[2][ct], 0, 0, 0);
                            acc[3][ct] = MFMA16(a3, b, acc[3][ct], 0, 0, 0);
                        }
                    }
                    if (cn < 3) stage_write(sA + ((cn + 1) & 1) * 16384, st, tid);
                    __syncthreads();
                }
            } else {
                const f16* BbS = WS1 + (size_t)(w8 * 3) * 32 * 512;   // h0 part
                const f16* BbB = WB1 + (size_t)(w8 * 3) * 32 * 512;   // h1 part
                const f16* h1r = H1P + (size_t)(s & 1) * 65536;       // h1(s-2)
                stage_issue(h0r, st, tid);
                stage_write(sA, st, tid);
                __syncthreads();
                for (int cn = 0; cn < 8; ++cn) {
                    if (cn < 7) {
                        const f16* nsrc = (cn + 1 < 4) ? h0r + (size_t)(cn + 1) * 16384
                                                       : h1r + (size_t)(cn - 3) * 16384;
                        stage_issue(nsrc, st, tid);
                    }
                    const f16* Ab = sA + (cn & 1) * 16384;
                    const f16* Bch = (cn < 4) ? BbS + (size_t)(cn * 8) * 512
                                              : BbB + (size_t)((cn - 4) * 8) * 512;
#pragma unroll
                    for (int k = 0; k < 8; ++k) {
                        const f16* ap = Ab + (size_t)(k * 4) * 512 + lo8;
                        f16x8 a0 = *(const f16x8*)(ap);
                        f16x8 a1 = *(const f16x8*)(ap + 512);
                        f16x8 a2 = *(const f16x8*)(ap + 1024);
                        f16x8 a3 = *(const f16x8*)(ap + 1536);
#pragma unroll
                        for (int ct = 0; ct < 3; ++ct) {
                            f16x8 b = *(const f16x8*)(Bch + (((size_t)(ct * 32 + k)) << 9) + lo8);
                            acc[0][ct] = MFMA16(a0, b, acc[0][ct], 0, 0, 0);
                            acc[1][ct] = MFMA16(a1, b, acc[1][ct], 0, 0, 0);
                            acc[2][ct] = MFMA16(a2, b, acc[2][ct], 0, 0, 0);
                            acc[3][ct] = MFMA16(a3, b, acc[3][ct], 0, 0, 0);
                        }
                    }
                    if (cn < 7) stage_write(sA + ((cn + 1) & 1) * 16384, st, tid);
                    __syncthreads();
                }
            }
            // epilogue: direct store + bias (waves own disjoint cols -> no atomics)
            const int cc16 = lane & 15;
            const int mq = (lane >> 4) << 2;
#pragma unroll
            for (int rt = 0; rt < 4; ++rt) {
                int rowb = rt * 16 + mq;
#pragma unroll
                for (int ct = 0; ct < 3; ++ct) {
                    int col = v * 48 + ct * 16 + cc16;
                    float bias = sBias[col];
#pragma unroll
                    for (int q = 0; q < 4; ++q)
                        sZ[(rowb + q) * 193 + col] = acc[rt][ct][q] + bias;
                }
            }
        }
        __syncthreads();

        if (active && tid < 128) {
            // local scan: exp + inclusive cumsum over this WG's 32 cols
            int g = tid >> 6, m = tid & 63;
            float run = 0.f;
            float* zb = sZ + m * 193 + 32 + g * 8;
#pragma unroll
            for (int vv = 0; vv < 4; ++vv)
#pragma unroll
                for (int jj = 0; jj < 8; ++jj) {
                    float e = __expf(zb[vv * 48 + jj]);
                    run += e;
                    zb[vv * 48 + jj] = run;
                }
            __hip_atomic_store(&PART[((size_t)(layer * 2 + g) * 32 + w) * 64 + m], run,
                               __ATOMIC_RELAXED, AGENT);
        }

        // ---------- barrier A (layer-local, flag array) ----------
        __syncthreads();   // implicit vmcnt(0): PART sc1 stores at coherence point
        if (tid == 0)
            __hip_atomic_store(&FA[wg * 16], s + 1, __ATOMIC_RELAXED, AGENT);
        if (tid < 32) {
            const int* fp = &FA[(layer * 32 + tid) * 16];
            while (__hip_atomic_load(fp, __ATOMIC_RELAXED, AGENT) < s + 1) {}
        }
        asm volatile("" ::: "memory");
        __syncthreads();

        if (active && tid < 128) {
            // global prefix/total over the 32 WG slices (sc1 loads)
            int g = tid >> 6, m = tid & 63;
            const float* pp = PART + ((size_t)(layer * 2 + g) * 32) * 64 + m;
            float pref = 0.f, tot = 0.f;
#pragma unroll
            for (int w2 = 0; w2 < 32; ++w2) {
                float val = __hip_atomic_load(&pp[(size_t)w2 * 64], __ATOMIC_RELAXED, AGENT);
                tot += val;
                pref += (w2 < w) ? val : 0.f;
            }
            sScl[m * 4 + g * 2]     = pref;
            sScl[m * 4 + g * 2 + 1] = 1.0f / tot;
        }
        __syncthreads();

        if (active) {
            // ---------- gate math + state update (8 cols/thread) ----------
            float pf = sScl[m_u * 4 + 0], rf = sScl[m_u * 4 + 1];
            float pi = sScl[m_u * 4 + 2], ri = sScl[m_u * 4 + 3];
            const float* zbase = sZ + m_u * 193 + v * 48;
            float hh[8];
#pragma unroll
            for (int jj = 0; jj < 8; ++jj) {
                float zi = zbase[jj];
                float zf = zbase[8 + jj];
                float zg = zbase[16 + jj];
                float zo = zbase[24 + jj];
                float cft = zbase[32 + jj];
                float cit = zbase[40 + jj];
                float ftil = (pf + cft) * rf;
                float itil = 1.0f - (pi + cit) * ri;
                float om = ftil * itil;
                float fi = fast_sigmoid(zf);
                float ii = fast_sigmoid(zi);
                float oo = fast_sigmoid(zo);
                float ch = fast_tanh(zg);
                float fh = fi * om + (ftil - om);
                float ih = ii * om + (itil - om);
                float cn = fh * c[jj] + ih * ch;
                c[jj] = cn;
                hh[jj] = oo * fast_tanh(cn);
            }

            // publish h as A-fragments (fp16, sc1), ring slots
            f16* HP = layer ? (H1P + (size_t)((s + 1) & 1) * 65536)   // h1(s-1)
                            : (H0P + (size_t)(s % 3) * 65536);        // h0(s)
#pragma unroll
            for (int p = 0; p < 4; ++p) {
                int jf = j0 + v * 8 + p * 2;
                int ktp = jf >> 5, sub = (jf >> 3) & 3, i0 = jf & 7;
                union { f16x2 h; int i; } hu;
                hu.h[0] = (f16)hh[2 * p]; hu.h[1] = (f16)hh[2 * p + 1];
                __hip_atomic_store(
                    (int*)(HP + ((size_t)(ktp * 4 + (m_u >> 4)) * 64 + (sub * 16 + (m_u & 15))) * 8 + i0),
                    hu.i, __ATOMIC_RELAXED, AGENT);
            }
            if (layer) {
#pragma unroll
                for (int p = 0; p < 4; ++p) {
                    int jf = j0 + v * 8 + p * 2;
                    *(float2*)(out + (size_t)t * 65536 + (size_t)m_u * 1024 + jf) =
                        make_float2(hh[2 * p], hh[2 * p + 1]);
                }
            }
            if (t == 255) {
#pragma unroll
                for (int p = 0; p < 4; ++p) {
                    int jf = j0 + v * 8 + p * 2;
                    *(float2*)(out + 16777216 + (size_t)layer * 65536 + (size_t)m_u * 1024 + jf) =
                        make_float2(hh[2 * p], hh[2 * p + 1]);
                    *(float2*)(out + 16908288 + (size_t)layer * 65536 + (size_t)m_u * 1024 + jf) =
                        make_float2(c[2 * p], c[2 * p + 1]);
                }
            }
        }

        // ---------- barrier B (flag array; h-publication rendezvous) ----------
        if (s < 256) {
            __syncthreads();   // drains all waves' h sc1 stores
            if (tid == 0)
                __hip_atomic_store(&FB[wg * 16], s + 1, __ATOMIC_RELAXED, AGENT);
            if (layer == 0) {
                if (tid < 32) {
                    const int* fp = &FB[tid * 16];
                    while (__hip_atomic_load(fp, __ATOMIC_RELAXED, AGENT) < s + 1) {}
                }
                // ring anti-overwrite: layer1 must have finished GEMM of step
                // s-1 (its barrier-A arrival value s) before layer0 enters
                // step s+1 and overwrites h0 slot (s+1)%3 = h0(s-2).
                if (tid >= 64 && tid < 96) {
                    const int* fp = &FA[(32 + (tid - 64)) * 16];
                    while (__hip_atomic_load(fp, __ATOMIC_RELAXED, AGENT) < s) {}
                }
            } else {
                if (tid < 32) {
                    const int* fp = &FB[(32 + tid) * 16];
                    while (__hip_atomic_load(fp, __ATOMIC_RELAXED, AGENT) < s + 1) {}
                }
                if (tid >= 64 && tid < 96) {   // h0(s) published for step s+1 GEMM
                    const int* fp = &FB[(tid - 64) * 16];
                    while (__hip_atomic_load(fp, __ATOMIC_RELAXED, AGENT) < s + 1) {}
                }
            }
            asm volatile("" ::: "memory");
            __syncthreads();
        }
    }
}

// ---------------- launch ----------------
extern "C" void kernel_launch(void* const* d_in, const int* in_sizes, int n_in,
                              void* d_out, int out_size, void* d_ws, size_t ws_size,
                              hipStream_t stream) {
    const float* x  = (const float*)d_in[0];
    const float* W0 = (const float*)d_in[1];
    const float* b0 = (const float*)d_in[2];
    const float* W1 = (const float*)d_in[3];
    const float* b1 = (const float*)d_in[4];
    float* out = (float*)d_out;

    char* ws = (char*)d_ws;
    f16* WB0    = (f16*)(ws + 0);           // 18874368
    f16* WB1    = (f16*)(ws + 18874368);    // 12582912
    f16* WS1    = (f16*)(ws + 31457280);    // 12582912
    f16* XP     = (f16*)(ws + 44040192);    // 16777216
    f16* H0P    = (f16*)(ws + 60817408);    // 3 x 131072 (ring)
    f16* H1P    = (f16*)(ws + 61210624);    // 2 x 131072 (ring)
    float* PART = (float*)(ws + 61472768);  // 131072 (uses 32768)
    int* FLAGS  = (int*)(ws + 61603840);    // 32768   (total 61.6 MiB, r3-proven)

    hipMemsetAsync(H0P, 0, 393216, stream);
    hipMemsetAsync(H1P, 0, 262144, stream);
    hipMemsetAsync(FLAGS, 0, 32768, stream);

    {   int n = 128 * 3 * 48 * 64;
        onlstm_pack_w<<<(n + 255) / 256, 256, 0, stream>>>(W0, WB0, 48, 0); }
    {   int n = 128 * 3 * 32 * 64;
        onlstm_pack_w<<<(n + 255) / 256, 256, 0, stream>>>(W1, WB1, 32, 1024); }
    {   int n = 128 * 3 * 32 * 64;
        onlstm_pack_w<<<(n + 255) / 256, 256, 0, stream>>>(W1, WS1, 32, 0); }
    {   int n = 256 * 16 * 4 * 64;
        onlstm_pack_x<<<(n + 255) / 256, 256, 0, stream>>>(x, XP); }

    const int smem_bytes = 116736;   // sA 65536 | sZ 49408 | sScl 1024 | sBias 768
    hipFuncSetAttribute((const void*)onlstm_main,
                        hipFuncAttributeMaxDynamicSharedMemorySize, smem_bytes);
    onlstm_main<<<NWG, 256, smem_bytes, stream>>>(WB0, WB1, WS1, XP, H0P, H1P,
                                                  PART, FLAGS, b0, b1, out);
}

// Round 5
// 6111.048 us; speedup vs baseline: 4.0287x; 4.0287x over previous
//
#include <hip/hip_runtime.h>
#include <hip/hip_fp16.h>

// ONLSTM fused 2-layer recurrent kernel for MI355X (gfx950), round 8.
// r7 resubmission: r7 returned "container failed twice" with no profile.
// Diagnosis: infra flake, not kernel -- r4 and r5<FRESH=1> were the same
// algorithm; r4 "failed twice", r5 ran and PASSED (mangled name ILi1EE
// proves the FRESH path executed). r7 was re-audited for deadlock (none:
// all flag targets monotone & reachable, no circular waits), OOB (layout
// identical to r5's proven 128.35 MB), and cross-iteration L2 staleness
// (validated empirically by r5 passing with this exact read path).
//
// Design (one mechanism changed vs r3's 5807 us baseline):
//   - fresh h-slot per timestep (H0P/H1P: 257 x 131072 B).
//   - h writes stay sc1 (drained by __syncthreads' implicit vmcnt(0)
//     before flag publish); h READS become plain cached loads: slot
//     addresses are cold per XCD, so the first miss fills L2 with fresh
//     data and the other ~15 WGs on that XCD hit L2. Replaces ~48 MB/step
//     of L2-bypassing L3 broadcast (r3's critical path) with ~3 MB/step
//     of per-XCD L2 fills.
//   - fresh slots remove the ring overwrite hazard -> layer0 free-runs
//     (no wait on layer1); layer1 self-paced behind it.
//   - barriers: r3's proven flag-array (1 store + parallel pollers).
//   - weights LDS-resident, 256 WGs (r6 proved streaming is latency-bound).

typedef _Float16 f16;
typedef _Float16 f16x8 __attribute__((ext_vector_type(8)));
typedef _Float16 f16x2 __attribute__((ext_vector_type(2)));
typedef float f32x4 __attribute__((ext_vector_type(4)));

#define NWG 256
#define AGENT __HIP_MEMORY_SCOPE_AGENT

// ---------------- pack kernels (unchanged, verified) ----------------
__global__ void onlstm_pack_w(const float* __restrict__ W, f16* __restrict__ dst,
                              int nkt, int krow0) {
    int idx = blockIdx.x * blockDim.x + threadIdx.x;
    int total = 128 * 3 * nkt * 64;
    if (idx >= total) return;
    int lane = idx & 63;
    int kt = (idx >> 6) % nkt;
    int ct = ((idx >> 6) / nkt) % 3;
    int w  = (idx >> 6) / (nkt * 3);
    int cc = lane & 15;
    int gate = 2 * ct + (cc >> 3);
    int col = gate * 1024 + (w << 3) + (cc & 7);
    int krow = krow0 + kt * 32 + ((lane >> 4) << 3);
    const float* src = W + (size_t)krow * 6144 + col;
    f16x8 v;
#pragma unroll
    for (int i = 0; i < 8; ++i) v[i] = (f16)src[(size_t)i * 6144];
    *(f16x8*)(dst + (size_t)idx * 8) = v;
}

__global__ void onlstm_pack_x(const float* __restrict__ x, f16* __restrict__ dst) {
    int idx = blockIdx.x * blockDim.x + threadIdx.x;
    if (idx >= 256 * 16 * 4 * 64) return;
    int lane = idx & 63;
    int rt = (idx >> 6) & 3;
    int kt = (idx >> 8) & 15;
    int t  = idx >> 12;
    int m = rt * 16 + (lane & 15);
    int k = kt * 32 + ((lane >> 4) << 3);
    const float* src = x + ((size_t)t * 64 + m) * 512 + k;
    f16x8 v;
#pragma unroll
    for (int i = 0; i < 8; ++i) v[i] = (f16)src[i];
    *(f16x8*)(dst + (size_t)idx * 8) = v;
}

__device__ __forceinline__ float fast_sigmoid(float x) {
    return 1.0f / (1.0f + __expf(-x));
}
__device__ __forceinline__ float fast_tanh(float x) {
    return 1.0f - 2.0f / (__expf(2.0f * x) + 1.0f);
}

// ---------------- main persistent kernel ----------------
// LDS: sB 147456 | sZ 64x49 f32 12544 | sPfx 2048 | sScl 1024 | sBias 256
__global__ __launch_bounds__(256, 1) void onlstm_main(
    const f16* __restrict__ WB0, const f16* __restrict__ WB1,
    const f16* __restrict__ WS1, const f16* __restrict__ XP,
    f16* __restrict__ H0P, f16* __restrict__ H1P,
    float* __restrict__ PART, int* __restrict__ FLAGS,
    const float* __restrict__ b0, const float* __restrict__ b1,
    float* __restrict__ out)
{
    extern __shared__ char smem[];
    f16*   sB    = (f16*)smem;
    float* sZ    = (float*)(smem + 147456);
    float* sPfx  = (float*)(smem + 160000);
    float* sScl  = (float*)(smem + 162048);
    float* sBias = (float*)(smem + 163072);

    const int tid = threadIdx.x;
    const int wg = blockIdx.x;
    const int layer = wg >> 7;
    const int w = wg & 127;
    const int lane = tid & 63;
    const int wv = tid >> 6;          // 0..3
    const int rtp = wv & 1;           // row-pair
    const int kh = wv >> 1;           // K-half
    const int j0 = w << 3;
    const int m_u = tid & 63;
    const int pr4 = tid >> 6;
    int* FA = FLAGS;                  // barrier-A flags, stride 16 ints (64B)
    int* FB = FLAGS + 4096;           // barrier-B flags

    // resident weights -> LDS (pre-kernel data: normal cached loads are safe)
    {
        const float4* s4 = (const float4*)(layer ? (WB1 + (size_t)w * (3 * 32 * 512))
                                                 : (WB0 + (size_t)w * (3 * 48 * 512)));
        float4* d4 = (float4*)sB;
        const int n = layer ? (3 * 32 * 64) : (3 * 48 * 64);
        for (int i = tid; i < n; i += 256) d4[i] = s4[i];
    }
    if (tid < 48) {
        int ct = tid >> 4, r = tid & 15;
        int gate = 2 * ct + (r >> 3);
        sBias[tid] = (layer ? b1 : b0)[gate * 1024 + j0 + (r & 7)];
    }
    float c0 = 0.f, c1 = 0.f;   // persistent cell state: (m_u, j0 + pr4*2 + {0,1})
    __syncthreads();

    for (int s = 0; s <= 256; ++s) {
        const int active = layer ? (s >= 1) : (s < 256);
        const int t = layer ? (s - 1) : s;

        if (active) {
            // init sZ with bias
            int m = tid >> 2, cb = (tid & 3) * 12;
            float* dst = sZ + m * 49 + cb;
            const float* bsrc = sBias + cb;
#pragma unroll
            for (int k = 0; k < 12; ++k) dst[k] = bsrc[k];
        }
        __syncthreads();

        if (active) {
            // ---------- GEMM (K-split across wave pairs) ----------
            f32x4 acc[2][3];
#pragma unroll
            for (int r = 0; r < 2; ++r)
#pragma unroll
                for (int c = 0; c < 3; ++c) { f32x4 z = {0.f,0.f,0.f,0.f}; acc[r][c] = z; }

            // h0(s-1) lives at fresh slot s (slot 0 = initial zeros)
            const f16* h0r = H0P + (size_t)s * 65536;
            const int abase = rtp * 1024 + lane * 8;

            if (layer == 0) {
                if (kh == 0) {
                    const f16* A1 = XP + (size_t)t * 32768;
#pragma unroll 8
                    for (int kt = 0; kt < 16; ++kt) {
                        const f16* ap = A1 + (size_t)kt * 2048 + abase;
                        f16x8 a0 = *(const f16x8*)ap;          // XP: pre-kernel, cached
                        f16x8 a1 = *(const f16x8*)(ap + 512);
#pragma unroll
                        for (int ct = 0; ct < 3; ++ct) {
                            f16x8 b = *(const f16x8*)(sB + ((size_t)(ct * 48 + kt) * 64 + lane) * 8);
                            acc[0][ct] = __builtin_amdgcn_mfma_f32_16x16x32_f16(a0, b, acc[0][ct], 0, 0, 0);
                            acc[1][ct] = __builtin_amdgcn_mfma_f32_16x16x32_f16(a1, b, acc[1][ct], 0, 0, 0);
                        }
                    }
#pragma unroll 8
                    for (int kt = 0; kt < 8; ++kt) {
                        const f16* ap = h0r + (size_t)kt * 2048 + abase;
                        f16x8 a0 = *(const f16x8*)ap;          // fresh slot: cached load
                        f16x8 a1 = *(const f16x8*)(ap + 512);
#pragma unroll
                        for (int ct = 0; ct < 3; ++ct) {
                            f16x8 b = *(const f16x8*)(sB + ((size_t)(ct * 48 + 16 + kt) * 64 + lane) * 8);
                            acc[0][ct] = __builtin_amdgcn_mfma_f32_16x16x32_f16(a0, b, acc[0][ct], 0, 0, 0);
                            acc[1][ct] = __builtin_amdgcn_mfma_f32_16x16x32_f16(a1, b, acc[1][ct], 0, 0, 0);
                        }
                    }
                } else {
#pragma unroll 8
                    for (int kt = 8; kt < 32; ++kt) {
                        const f16* ap = h0r + (size_t)kt * 2048 + abase;
                        f16x8 a0 = *(const f16x8*)ap;
                        f16x8 a1 = *(const f16x8*)(ap + 512);
#pragma unroll
                        for (int ct = 0; ct < 3; ++ct) {
                            f16x8 b = *(const f16x8*)(sB + ((size_t)(ct * 48 + 16 + kt) * 64 + lane) * 8);
                            acc[0][ct] = __builtin_amdgcn_mfma_f32_16x16x32_f16(a0, b, acc[0][ct], 0, 0, 0);
                            acc[1][ct] = __builtin_amdgcn_mfma_f32_16x16x32_f16(a1, b, acc[1][ct], 0, 0, 0);
                        }
                    }
                }
            } else {
                if (kh == 0) {
                    const f16* BS = WS1 + (size_t)w * (3 * 32 * 512);  // pre-kernel, cached
#pragma unroll 8
                    for (int kt = 0; kt < 32; ++kt) {
                        const f16* ap = h0r + (size_t)kt * 2048 + abase;
                        f16x8 a0 = *(const f16x8*)ap;
                        f16x8 a1 = *(const f16x8*)(ap + 512);
#pragma unroll
                        for (int ct = 0; ct < 3; ++ct) {
                            f16x8 b = *(const f16x8*)(BS + ((size_t)(ct * 32 + kt) * 64 + lane) * 8);
                            acc[0][ct] = __builtin_amdgcn_mfma_f32_16x16x32_f16(a0, b, acc[0][ct], 0, 0, 0);
                            acc[1][ct] = __builtin_amdgcn_mfma_f32_16x16x32_f16(a1, b, acc[1][ct], 0, 0, 0);
                        }
                    }
                } else {
                    // h1(s-2) lives at fresh slot s-1 (slot 0 = initial zeros)
                    const f16* h1r = H1P + (size_t)(s - 1) * 65536;
#pragma unroll 8
                    for (int kt = 0; kt < 32; ++kt) {
                        const f16* ap = h1r + (size_t)kt * 2048 + abase;
                        f16x8 a0 = *(const f16x8*)ap;
                        f16x8 a1 = *(const f16x8*)(ap + 512);
#pragma unroll
                        for (int ct = 0; ct < 3; ++ct) {
                            f16x8 b = *(const f16x8*)(sB + ((size_t)(ct * 32 + kt) * 64 + lane) * 8);
                            acc[0][ct] = __builtin_amdgcn_mfma_f32_16x16x32_f16(a0, b, acc[0][ct], 0, 0, 0);
                            acc[1][ct] = __builtin_amdgcn_mfma_f32_16x16x32_f16(a1, b, acc[1][ct], 0, 0, 0);
                        }
                    }
                }
            }
            // epilogue: accumulate partials into sZ (bias pre-loaded)
            const int mq = ((lane >> 4) << 2);
            const int colb = lane & 15;
#pragma unroll
            for (int r = 0; r < 2; ++r) {
                int mrow = rtp * 32 + r * 16 + mq;
#pragma unroll
                for (int ct = 0; ct < 3; ++ct) {
                    int col = ct * 16 + colb;
#pragma unroll
                    for (int q = 0; q < 4; ++q)
                        atomicAdd(&sZ[(mrow + q) * 49 + col], acc[r][ct][q]);
                }
            }
        }
        __syncthreads();

        if (active && tid < 128) {
            // local scan: exp + inclusive cumsum over 8 cols (g = f~ or i~)
            int g = tid >> 6, m = tid & 63;
            float run = 0.f;
            float* zp = sZ + m * 49 + 32 + g * 8;
#pragma unroll
            for (int jj = 0; jj < 8; ++jj) {
                float e = __expf(zp[jj]);
                run += e;
                zp[jj] = run;
            }
            __hip_atomic_store(&PART[((size_t)(layer * 2 + g) * 128 + w) * 64 + m], run,
                               __ATOMIC_RELAXED, AGENT);
        }

        // ---------- barrier A (layer-local, flag array, r3-proven) ----------
        __syncthreads();   // implicit vmcnt(0): all waves' sc1 stores at coherence point
        if (tid == 0)
            __hip_atomic_store(&FA[wg * 16], s + 1, __ATOMIC_RELAXED, AGENT);
        if (tid < 128) {
            const int* fp = &FA[(layer * 128 + tid) * 16];
            while (__hip_atomic_load(fp, __ATOMIC_RELAXED, AGENT) < s + 1) {}
        }
        asm volatile("" ::: "memory");
        __syncthreads();

        if (active) {
            // global prefix/total, half-split across the 4 waves (sc1 loads)
            int g = pr4 & 1, half = pr4 >> 1;
            const float* pp = PART + ((size_t)(layer * 2 + g) * 128 + half * 64) * 64 + m_u;
            float pref = 0.f, tot = 0.f;
            int wrel = w - half * 64;
#pragma unroll 16
            for (int w2 = 0; w2 < 64; ++w2) {
                float v = __hip_atomic_load(&pp[(size_t)w2 * 64], __ATOMIC_RELAXED, AGENT);
                tot += v;
                pref += (w2 < wrel) ? v : 0.f;
            }
            float* q = sPfx + ((size_t)(m_u * 2 + g) * 2 + half) * 2;
            q[0] = pref; q[1] = tot;
        }
        __syncthreads();
        if (active && tid < 128) {
            int g = tid >> 6, m = tid & 63;
            float* q = sPfx + (size_t)(m * 2 + g) * 4;
            sScl[m * 4 + g * 2]     = q[0] + q[2];
            sScl[m * 4 + g * 2 + 1] = 1.0f / (q[1] + q[3]);
        }
        __syncthreads();

        if (active) {
            // ---------- gate math + state update (2 cols/thread) ----------
            float pf = sScl[m_u * 4 + 0], rf = sScl[m_u * 4 + 1];
            float pi = sScl[m_u * 4 + 2], ri = sScl[m_u * 4 + 3];
            int zb = m_u * 49;
            float cc[2] = {c0, c1}, hh[2];
#pragma unroll
            for (int q = 0; q < 2; ++q) {
                int jj = pr4 * 2 + q;
                float zi = sZ[zb + jj];
                float zf = sZ[zb + 8 + jj];
                float zg = sZ[zb + 16 + jj];
                float zo = sZ[zb + 24 + jj];
                float cft = sZ[zb + 32 + jj];
                float cit = sZ[zb + 40 + jj];
                float ftil = (pf + cft) * rf;
                float itil = 1.0f - (pi + cit) * ri;
                float om = ftil * itil;
                float fi = fast_sigmoid(zf);
                float ii = fast_sigmoid(zi);
                float oo = fast_sigmoid(zo);
                float ch = fast_tanh(zg);
                float fh = fi * om + (ftil - om);
                float ih = ii * om + (itil - om);
                float cn = fh * cc[q] + ih * ch;
                cc[q] = cn;
                hh[q] = oo * fast_tanh(cn);
            }
            c0 = cc[0]; c1 = cc[1];

            // publish h as A-fragments (fp16, sc1 write-through to fresh slot)
            int jfull = j0 + pr4 * 2;
            int ktp = jfull >> 5;
            int quad = (jfull >> 3) & 3;
            int i0 = jfull & 7;
            f16* HP = layer ? (H1P + (size_t)s * 65536)        // h1(s-1) -> slot s
                            : (H0P + (size_t)(s + 1) * 65536); // h0(s)   -> slot s+1
            union { f16x2 h; int i; } hu;
            hu.h[0] = (f16)hh[0]; hu.h[1] = (f16)hh[1];
            __hip_atomic_store(
                (int*)(HP + ((size_t)(ktp * 4 + (m_u >> 4)) * 64 + (quad * 16 + (m_u & 15))) * 8 + i0),
                hu.i, __ATOMIC_RELAXED, AGENT);

            if (layer)
                *(float2*)(out + (size_t)t * 65536 + (size_t)m_u * 1024 + jfull) = make_float2(hh[0], hh[1]);
            if (t == 255) {
                *(float2*)(out + 16777216 + (size_t)layer * 65536 + (size_t)m_u * 1024 + jfull) = make_float2(hh[0], hh[1]);
                *(float2*)(out + 16908288 + (size_t)layer * 65536 + (size_t)m_u * 1024 + jfull) = make_float2(cc[0], cc[1]);
            }
        }

        // ---------- barrier B (flag array; layer0 decoupled) ----------
        if (s < 256) {
            __syncthreads();   // drains all waves' h sc1 stores
            if (tid == 0)
                __hip_atomic_store(&FB[wg * 16], s + 1, __ATOMIC_RELAXED, AGENT);
            if (layer == 0) {
                // fresh slots: no anti-overwrite hazard, no wait on layer1.
                if (tid < 128) {
                    const int* fp = &FB[tid * 16];
                    while (__hip_atomic_load(fp, __ATOMIC_RELAXED, AGENT) < s + 1) {}
                }
            } else {
                // layer1 needs h0(s) from layer0 AND h1(s-1) from layer1.
                const int* fp = &FB[tid * 16];
                while (__hip_atomic_load(fp, __ATOMIC_RELAXED, AGENT) < s + 1) {}
            }
            asm volatile("" ::: "memory");
            __syncthreads();
        }
    }
}

// ---------------- launch ----------------
extern "C" void kernel_launch(void* const* d_in, const int* in_sizes, int n_in,
                              void* d_out, int out_size, void* d_ws, size_t ws_size,
                              hipStream_t stream) {
    const float* x  = (const float*)d_in[0];
    const float* W0 = (const float*)d_in[1];
    const float* b0 = (const float*)d_in[2];
    const float* W1 = (const float*)d_in[3];
    const float* b1 = (const float*)d_in[4];
    float* out = (float*)d_out;

    char* ws = (char*)d_ws;
    f16* WB0    = (f16*)(ws + 0);           // 18874368
    f16* WB1    = (f16*)(ws + 18874368);    // 12582912
    f16* WS1    = (f16*)(ws + 31457280);    // 12582912
    f16* XP     = (f16*)(ws + 44040192);    // 16777216
    f16* H0P    = (f16*)(ws + 60817408);    // 257 x 131072 = 33685504
    f16* H1P    = (f16*)(ws + 94502912);    // 257 x 131072 = 33685504
    float* PART = (float*)(ws + 128188416); // 131072
    int* FLAGS  = (int*)(ws + 128319488);   // 32768  (total 128352256 B)

    hipMemsetAsync(H0P, 0, 131072, stream);   // slot 0 = h0(-1) = 0
    hipMemsetAsync(H1P, 0, 131072, stream);   // slot 0 = h1(-1) = 0
    hipMemsetAsync(FLAGS, 0, 32768, stream);

    {   int n = 128 * 3 * 48 * 64;
        onlstm_pack_w<<<(n + 255) / 256, 256, 0, stream>>>(W0, WB0, 48, 0); }
    {   int n = 128 * 3 * 32 * 64;
        onlstm_pack_w<<<(n + 255) / 256, 256, 0, stream>>>(W1, WB1, 32, 1024); }
    {   int n = 128 * 3 * 32 * 64;
        onlstm_pack_w<<<(n + 255) / 256, 256, 0, stream>>>(W1, WS1, 32, 0); }
    {   int n = 256 * 16 * 4 * 64;
        onlstm_pack_x<<<(n + 255) / 256, 256, 0, stream>>>(x, XP); }

    const int smem_bytes = 163328;
    hipFuncSetAttribute((const void*)onlstm_main,
                        hipFuncAttributeMaxDynamicSharedMemorySize, smem_bytes);
    onlstm_main<<<NWG, 256, smem_bytes, stream>>>(WB0, WB1, WS1, XP, H0P, H1P,
                                                  PART, FLAGS, b0, b1, out);
}